// Round 9
// baseline (172.932 us; speedup 1.0000x reference)
//
#include <hip/hip_runtime.h>
#include <hip/hip_bf16.h>

// SAGAN self-attention, MI355X gfx950. B=4, C=64, H=W=128, N=16384, M=4096.
// fp32 in/out. Round 9:
//  - score MFMA K32 -> K16 (only 9 K slots live): halves score MFMA time.
//  - n-tile 64, 8 waves split m-halves, grid 1024 -> 4 blocks/CU (2x occupancy);
//    cross-wave-pair acc/l merge in LDS epilogue.
//  - gG pi-permuted per 32-m chunk so PV G-frag pair = one b128 LDS read.
//  - staging c=tid&31 -> 2-way (free) LDS write banks.
// Verified MFMA layouts: A[row=lane&15][k=8q+j(K32)/4q+j(K16)],
// B same k-map col=lane&15, C/D[row=4q+r][col=lane&15].

typedef __attribute__((ext_vector_type(4))) float f32x4;
typedef __attribute__((ext_vector_type(8))) short s16x8;
typedef __attribute__((ext_vector_type(4))) short s16x4;

__device__ __forceinline__ unsigned short f32_bf16(float f) {
    unsigned int u = __float_as_uint(f);
    return (unsigned short)((u + 0x7fffu + ((u >> 16) & 1u)) >> 16);  // RNE
}
__device__ __forceinline__ unsigned int pk_bf16(float a, float b) {
    return (unsigned int)f32_bf16(a) | ((unsigned int)f32_bf16(b) << 16);
}
__device__ __forceinline__ unsigned int pk_rh(float a, float b) {   // round-half-up
    unsigned int au = __float_as_uint(a) + 0x8000u;
    unsigned int bu = __float_as_uint(b) + 0x8000u;
    return __builtin_amdgcn_perm(bu, au, 0x07060302u);
}
__device__ __forceinline__ unsigned int pk_tr(float a, float b) {   // truncate
    return __builtin_amdgcn_perm(__float_as_uint(b), __float_as_uint(a), 0x07060302u);
}

// ---------------- proj: theta/phi/g 1x1 conv + 2x2 maxpool, MFMA ----------------
// Grid 512 = b(4) x mh(64) x ph(2). Block 256 thr = 4 waves.
__global__ __launch_bounds__(256) void proj_kernel(
    const float* __restrict__ x,
    const float* __restrict__ w_theta, const float* __restrict__ w_phi,
    const float* __restrict__ w_g,
    __hip_bfloat16* __restrict__ thG,   // [b][n][8]  (theta * log2e)
    __hip_bfloat16* __restrict__ phG,   // [b][m][8]
    __hip_bfloat16* __restrict__ gG)    // [b][32][4096], pi-permuted per 32-m chunk
{
    __shared__ __align__(16) unsigned short x_s[128 * 72];  // [pix][c], 144 B rows
    int tid = threadIdx.x;
    int bx = blockIdx.x;
    int b = bx >> 7, mh = (bx >> 1) & 63, ph = bx & 1;

    // phase 1: float4 loads (c-pair per thread), bf16 c-pair-packed u32 transpose
    {
        int cp = tid >> 3, s = tid & 7;
        const float* xb = x + ((size_t)b << 20) + (size_t)(2 * mh) * 128 + 64 * ph;
        const float* p0r = xb + ((size_t)(2 * cp) << 14);
        const float* p1r = p0r + (1 << 14);
#pragma unroll
        for (int py = 0; py < 2; py++)
#pragma unroll
            for (int t = 0; t < 2; t++) {
                int pxl = 4 * s + 32 * t;
                float4 a = *(const float4*)(p0r + py * 128 + pxl);
                float4 c = *(const float4*)(p1r + py * 128 + pxl);
                int pix = py * 64 + pxl;
                *(unsigned int*)&x_s[(pix + 0) * 72 + 2 * cp] = pk_rh(a.x, c.x);
                *(unsigned int*)&x_s[(pix + 1) * 72 + 2 * cp] = pk_rh(a.y, c.y);
                *(unsigned int*)&x_s[(pix + 2) * 72 + 2 * cp] = pk_rh(a.z, c.z);
                *(unsigned int*)&x_s[(pix + 3) * 72 + 2 * cp] = pk_rh(a.w, c.w);
            }
    }

    int lane = tid & 63, w = tid >> 6;
    int q = lane >> 4, nl = lane & 15;

    // weight A-frags: A[row=ch_local=nl][k = 32*ks + 8q + j]
    s16x8 A[3][2];
#pragma unroll
    for (int CT = 0; CT < 3; CT++) {
        const float* wsrc;
        float scale = 1.0f;
        if (CT == 0) {
            if (nl < 8) { wsrc = w_theta + nl * 64; scale = 1.44269504f; }
            else        { wsrc = w_phi + (nl - 8) * 64; }
        } else if (CT == 1) wsrc = w_g + nl * 64;
        else                wsrc = w_g + (16 + nl) * 64;
#pragma unroll
        for (int ks = 0; ks < 2; ks++) {
            const float4* p4 = (const float4*)(wsrc + 32 * ks + 8 * q);
            float4 a0 = p4[0], a1 = p4[1];
            s16x8 f;
            f[0] = (short)f32_bf16(a0.x * scale); f[1] = (short)f32_bf16(a0.y * scale);
            f[2] = (short)f32_bf16(a0.z * scale); f[3] = (short)f32_bf16(a0.w * scale);
            f[4] = (short)f32_bf16(a1.x * scale); f[5] = (short)f32_bf16(a1.y * scale);
            f[6] = (short)f32_bf16(a1.z * scale); f[7] = (short)f32_bf16(a1.w * scale);
            A[CT][ks] = f;
        }
    }
    __syncthreads();

    // phase 2: wave w owns px-tiles {w (py=0), w+4 (py=1)}
    f32x4 acc[3][2];
#pragma unroll
    for (int ti = 0; ti < 2; ti++) {
        int tile = w + 4 * ti;
        const unsigned short* rb = x_s + (16 * tile + nl) * 72;
        s16x8 B0 = *(const s16x8*)(rb + 8 * q);
        s16x8 B1 = *(const s16x8*)(rb + 32 + 8 * q);
#pragma unroll
        for (int CT = 0; CT < 3; CT++) {
            f32x4 d = (f32x4){0.f, 0.f, 0.f, 0.f};
            d = __builtin_amdgcn_mfma_f32_16x16x32_bf16(A[CT][0], B0, d, 0, 0, 0);
            d = __builtin_amdgcn_mfma_f32_16x16x32_bf16(A[CT][1], B1, d, 0, 0, 0);
            acc[CT][ti] = d;
        }
    }

    // theta store: [n][8] layout, uint2 per (q<2, ti)
    if (q < 2) {
        unsigned short* thb = (unsigned short*)thG + ((size_t)b << 14) * 8;
#pragma unroll
        for (int ti = 0; ti < 2; ti++) {
            int n = (2 * mh + ti) * 128 + 64 * ph + 16 * w + nl;
            uint2 tv;
            tv.x = pk_bf16(acc[0][ti][0], acc[0][ti][1]);
            tv.y = pk_bf16(acc[0][ti][2], acc[0][ti][3]);
            *(uint2*)(thb + (size_t)n * 8 + 4 * q) = tv;
        }
    }

    // 2x2 maxpool: py via ti-pair, px via shfl_xor(1)
    float pool[3][4];
#pragma unroll
    for (int CT = 0; CT < 3; CT++)
#pragma unroll
        for (int r = 0; r < 4; r++) {
            float a = fmaxf(acc[CT][0][r], acc[CT][1][r]);
            pool[CT][r] = fmaxf(a, __shfl_xor(a, 1));
        }

    int mm = 8 * w + (nl >> 1);                       // m within 32-chunk
    int mbase = mh * 64 + ph * 32;
    if ((nl & 1) == 0) {
        if (q >= 2) {   // phi channels 4(q-2)+r, compact [m][8]
            uint2 pv;
            pv.x = pk_bf16(pool[0][0], pool[0][1]);
            pv.y = pk_bf16(pool[0][2], pool[0][3]);
            *(uint2*)((unsigned short*)phG + ((size_t)(b * 4096 + mbase + mm)) * 8 + (q - 2) * 4) = pv;
        }
        // pi: m=16h+4t+r -> p=8t+4h+r
        int p = 8 * ((mm >> 2) & 3) + 4 * ((mm >> 4) & 1) + (mm & 3);
        int mstore = mbase + p;
#pragma unroll
        for (int CT = 1; CT < 3; CT++)
#pragma unroll
            for (int r = 0; r < 4; r++) {
                int cg = 16 * (CT - 1) + 4 * q + r;
                ((unsigned short*)gG)[((size_t)(b * 32 + cg) << 12) + mstore] =
                    f32_bf16(pool[CT][r]);
            }
    }
}

// ---------------- attn: K16 score MFMA -> exp2 -> K16 PV MFMA ----------------
// Grid 1024 = b(4) x n-tile(256, 64 n each). Block 512 thr = 8 waves.
// Wave w: n-group ng=w&3 (16 n), m-half half=w>>2 (cc 0..3 / 4..7 per st).
#define GSTR 528   // g_s row stride bytes (256 m bf16 + 16 pad)

__global__ __launch_bounds__(512) void attn_kernel(
    const __hip_bfloat16* __restrict__ thG, const __hip_bfloat16* __restrict__ phG,
    const __hip_bfloat16* __restrict__ gG,
    const float* __restrict__ w_o, const float* __restrict__ gamma,
    const float* __restrict__ x, float* __restrict__ out)
{
    __shared__ __align__(16) unsigned char smem[32 * GSTR];   // 16896 B
    unsigned char* g_s = smem;                 // [32 c][GSTR]
    unsigned char* O_s = smem;                 // epilogue overlay [64][80 B]
    float* M_s = (float*)(smem + 6144);        // merge [4 ng][64 lane][10 f32]

    int tid = threadIdx.x, lane = tid & 63, w = tid >> 6;
    int q = lane >> 4, nl = lane & 15;
    int ng = w & 3, half = w >> 2;
    int bx = blockIdx.x;
    int b  = bx >> 8;
    int n0 = (bx & 255) << 6;
    int nw = n0 + ng * 16;

    const unsigned short* thb = (const unsigned short*)thG + ((size_t)b << 14) * 8;
    const unsigned short* phb = (const unsigned short*)phG + ((size_t)b << 12) * 8;
    const unsigned short* ggb = (const unsigned short*)gG + ((size_t)b << 17);

    // theta B-frag (K16): B[k=c=4q+j][col=n=nl]; q2/j0 = shift (cancels in softmax)
    s16x4 BT = (s16x4){0, 0, 0, 0};
    if (q < 2) {
        uint2 t = *(const uint2*)(thb + (size_t)(nw + nl) * 8 + 4 * q);
        BT = *(s16x4*)&t;
    } else if (q == 2) BT[0] = (short)0xC167;   // bf16(-14.4375)
    // phi A-frag const part: q2/j0 -> k=8 slot = 1.0
    s16x4 Fc = (s16x4){0, 0, 0, 0};
    if (q == 2) Fc[0] = (short)0x3F80;

    f32x4 acc0 = (f32x4){0.f, 0.f, 0.f, 0.f};
    f32x4 acc1 = (f32x4){0.f, 0.f, 0.f, 0.f};
    float l = 0.f;

    int cs = tid & 31, ss = tid >> 5;   // staging: row cs, 32B seg ss (2-way banks)

    for (int st = 0; st < 16; st++) {
        int m0 = st << 8;
        __syncthreads();
        {   // stage g: 32 c x 256 m bf16
            const uint4* src = (const uint4*)(ggb + (cs << 12) + m0 + ss * 16);
            uint4* dst = (uint4*)(g_s + cs * GSTR + ss * 32);
            dst[0] = src[0]; dst[1] = src[1];
        }
        __syncthreads();
#pragma unroll
        for (int cc = 0; cc < 4; cc++) {
            int mloc = (half * 4 + cc) << 5;
            int mg = m0 + mloc;
            s16x4 F0 = Fc, F1 = Fc;
            if (q < 2) {
                uint2 u = *(const uint2*)(phb + (size_t)(mg + nl) * 8 + 4 * q);
                F0 = *(s16x4*)&u;
                uint2 v = *(const uint2*)(phb + (size_t)(mg + 16 + nl) * 8 + 4 * q);
                F1 = *(s16x4*)&v;
            }
            f32x4 z = (f32x4){0.f, 0.f, 0.f, 0.f};
            f32x4 sc0 = __builtin_amdgcn_mfma_f32_16x16x16bf16_1k(F0, BT, z, 0, 0, 0);
            f32x4 sc1 = __builtin_amdgcn_mfma_f32_16x16x16bf16_1k(F1, BT, z, 0, 0, 0);
            float e0 = __builtin_amdgcn_exp2f(sc0[0]);
            float e1 = __builtin_amdgcn_exp2f(sc0[1]);
            float e2 = __builtin_amdgcn_exp2f(sc0[2]);
            float e3 = __builtin_amdgcn_exp2f(sc0[3]);
            float f0 = __builtin_amdgcn_exp2f(sc1[0]);
            float f1 = __builtin_amdgcn_exp2f(sc1[1]);
            float f2 = __builtin_amdgcn_exp2f(sc1[2]);
            float f3 = __builtin_amdgcn_exp2f(sc1[3]);
            l += ((e0 + e1) + (e2 + e3)) + ((f0 + f1) + (f2 + f3));
            uint2 u0 = make_uint2(pk_tr(e0, e1), pk_tr(e2, e3));  // m=4q+r
            uint2 u1 = make_uint2(pk_tr(f0, f1), pk_tr(f2, f3));  // m=16+4q+r
            s16x4 P0 = *(s16x4*)&u0;
            s16x4 P1 = *(s16x4*)&u1;
            // pi-permuted g: one b128 per c-row = [frag-a | frag-b]
            s16x8 G0 = *(const s16x8*)(g_s + nl * GSTR + (mloc + 8 * q) * 2);
            s16x8 G1 = *(const s16x8*)(g_s + (nl + 16) * GSTR + (mloc + 8 * q) * 2);
            s16x4 G0a = __builtin_shufflevector(G0, G0, 0, 1, 2, 3);
            s16x4 G0b = __builtin_shufflevector(G0, G0, 4, 5, 6, 7);
            s16x4 G1a = __builtin_shufflevector(G1, G1, 0, 1, 2, 3);
            s16x4 G1b = __builtin_shufflevector(G1, G1, 4, 5, 6, 7);
            acc0 = __builtin_amdgcn_mfma_f32_16x16x16bf16_1k(G0a, P0, acc0, 0, 0, 0);
            acc0 = __builtin_amdgcn_mfma_f32_16x16x16bf16_1k(G0b, P1, acc0, 0, 0, 0);
            acc1 = __builtin_amdgcn_mfma_f32_16x16x16bf16_1k(G1a, P0, acc1, 0, 0, 0);
            acc1 = __builtin_amdgcn_mfma_f32_16x16x16bf16_1k(G1b, P1, acc1, 0, 0, 0);
        }
    }

    // denominator partial: reduce over quads (this wave's m-half)
    l += __shfl_xor(l, 16);
    l += __shfl_xor(l, 32);

    float gam = gamma[0];
    __syncthreads();          // g_s reads done; overlay M_s/O_s
    if (half == 1) {          // m-high waves publish partials
        float* p = M_s + (size_t)(ng * 64 + lane) * 10;
        p[0] = acc0[0]; p[1] = acc0[1]; p[2] = acc0[2]; p[3] = acc0[3];
        p[4] = acc1[0]; p[5] = acc1[1]; p[6] = acc1[2]; p[7] = acc1[3];
        p[8] = l;
    }
    __syncthreads();
    if (half == 0) {          // m-low waves merge, normalize, write O
        const float* p = M_s + (size_t)(ng * 64 + lane) * 10;
        acc0[0] += p[0]; acc0[1] += p[1]; acc0[2] += p[2]; acc0[3] += p[3];
        acc1[0] += p[4]; acc1[1] += p[5]; acc1[2] += p[6]; acc1[3] += p[7];
        float linv = 1.0f / (l + p[8]);
        acc0 *= linv;
        acc1 *= linv;
        int n_loc = ng * 16 + nl;
        uint2 ov;
        ov.x = pk_bf16(acc0[0], acc0[1]);
        ov.y = pk_bf16(acc0[2], acc0[3]);
        *(uint2*)(O_s + n_loc * 80 + q * 8) = ov;          // c = 4q..4q+3
        ov.x = pk_bf16(acc1[0], acc1[1]);
        ov.y = pk_bf16(acc1[2], acc1[3]);
        *(uint2*)(O_s + n_loc * 80 + 32 + q * 8) = ov;     // c = 16+4q..
    }
    __syncthreads();

    // epilogue: w_o MFMA (K32), wave pair splits output-channel groups
    s16x8 OB = *(const s16x8*)(O_s + (ng * 16 + nl) * 80 + q * 16);
#pragma unroll
    for (int g2 = 0; g2 < 2; g2++) {
        int g4 = half * 2 + g2;
        const float4* wr = (const float4*)(w_o + (size_t)(g4 * 16 + nl) * 32 + q * 8);
        float4 a0 = wr[0], a1 = wr[1];
        s16x8 WO;
        WO[0] = (short)f32_bf16(a0.x); WO[1] = (short)f32_bf16(a0.y);
        WO[2] = (short)f32_bf16(a0.z); WO[3] = (short)f32_bf16(a0.w);
        WO[4] = (short)f32_bf16(a1.x); WO[5] = (short)f32_bf16(a1.y);
        WO[6] = (short)f32_bf16(a1.z); WO[7] = (short)f32_bf16(a1.w);
        f32x4 d = (f32x4){0.f, 0.f, 0.f, 0.f};
        d = __builtin_amdgcn_mfma_f32_16x16x32_bf16(WO, OB, d, 0, 0, 0);
#pragma unroll
        for (int r = 0; r < 4; r++) {
            int cc = g4 * 16 + q * 4 + r;
            size_t gi = (((size_t)(b * 64 + cc)) << 14) + nw + nl;
            out[gi] = gam * d[r] + x[gi];
        }
    }
}

extern "C" void kernel_launch(void* const* d_in, const int* in_sizes, int n_in,
                              void* d_out, int out_size, void* d_ws, size_t ws_size,
                              hipStream_t stream) {
    const float* x       = (const float*)d_in[0];
    const float* w_theta = (const float*)d_in[1];
    const float* w_phi   = (const float*)d_in[2];
    const float* w_g     = (const float*)d_in[3];
    const float* w_o     = (const float*)d_in[4];
    const float* gamma   = (const float*)d_in[5];
    float* out = (float*)d_out;

    __hip_bfloat16* thG = (__hip_bfloat16*)d_ws;        // 4*16384*8 = 1 MB
    __hip_bfloat16* phG = thG + 524288;                 // 4*4096*8  = 256 KB
    __hip_bfloat16* gG  = phG + 131072;                 // 4*32*4096 = 1 MB

    proj_kernel<<<512, 256, 0, stream>>>(x, w_theta, w_phi, w_g, thG, phG, gG);
    attn_kernel<<<1024, 512, 0, stream>>>(thG, phG, gG, w_o, gamma, x, out);
}

// Round 10
// 153.636 us; speedup vs baseline: 1.1256x; 1.1256x over previous
//
#include <hip/hip_runtime.h>
#include <hip/hip_bf16.h>

// SAGAN self-attention, MI355X gfx950. B=4, C=64, H=W=128, N=16384, M=4096.
// fp32 in/out. Round 10: round-8 shape (full-m waves) + double-buffered LDS
// staging w/ register prefetch (1 barrier/st), K16 score MFMA, pi-permuted
// b128 G reads, l via ones-MFMA (no VALU adds / shfl reduce).
// Verified MFMA layouts: A[row=lane&15][k=8q+j(K32)/4q+j(K16)],
// B same k-map col=lane&15, C/D[row=4q+r][col=lane&15].

typedef __attribute__((ext_vector_type(4))) float f32x4;
typedef __attribute__((ext_vector_type(8))) short s16x8;
typedef __attribute__((ext_vector_type(4))) short s16x4;

__device__ __forceinline__ unsigned short f32_bf16(float f) {
    unsigned int u = __float_as_uint(f);
    return (unsigned short)((u + 0x7fffu + ((u >> 16) & 1u)) >> 16);  // RNE
}
__device__ __forceinline__ unsigned int pk_bf16(float a, float b) {
    return (unsigned int)f32_bf16(a) | ((unsigned int)f32_bf16(b) << 16);
}
__device__ __forceinline__ unsigned int pk_rh(float a, float b) {   // round-half-up
    unsigned int au = __float_as_uint(a) + 0x8000u;
    unsigned int bu = __float_as_uint(b) + 0x8000u;
    return __builtin_amdgcn_perm(bu, au, 0x07060302u);
}
__device__ __forceinline__ unsigned int pk_tr(float a, float b) {   // truncate
    return __builtin_amdgcn_perm(__float_as_uint(b), __float_as_uint(a), 0x07060302u);
}

// ---------------- proj: theta/phi/g 1x1 conv + 2x2 maxpool, MFMA ----------------
// (verbatim round 9 — passed, emits pi-permuted gG)
__global__ __launch_bounds__(256) void proj_kernel(
    const float* __restrict__ x,
    const float* __restrict__ w_theta, const float* __restrict__ w_phi,
    const float* __restrict__ w_g,
    __hip_bfloat16* __restrict__ thG,   // [b][n][8]  (theta * log2e)
    __hip_bfloat16* __restrict__ phG,   // [b][m][8]
    __hip_bfloat16* __restrict__ gG)    // [b][32][4096], pi-permuted per 32-m chunk
{
    __shared__ __align__(16) unsigned short x_s[128 * 72];  // [pix][c], 144 B rows
    int tid = threadIdx.x;
    int bx = blockIdx.x;
    int b = bx >> 7, mh = (bx >> 1) & 63, ph = bx & 1;

    {   // phase 1: float4 loads (c-pair per thread), packed u32 LDS transpose
        int cp = tid >> 3, s = tid & 7;
        const float* xb = x + ((size_t)b << 20) + (size_t)(2 * mh) * 128 + 64 * ph;
        const float* p0r = xb + ((size_t)(2 * cp) << 14);
        const float* p1r = p0r + (1 << 14);
#pragma unroll
        for (int py = 0; py < 2; py++)
#pragma unroll
            for (int t = 0; t < 2; t++) {
                int pxl = 4 * s + 32 * t;
                float4 a = *(const float4*)(p0r + py * 128 + pxl);
                float4 c = *(const float4*)(p1r + py * 128 + pxl);
                int pix = py * 64 + pxl;
                *(unsigned int*)&x_s[(pix + 0) * 72 + 2 * cp] = pk_rh(a.x, c.x);
                *(unsigned int*)&x_s[(pix + 1) * 72 + 2 * cp] = pk_rh(a.y, c.y);
                *(unsigned int*)&x_s[(pix + 2) * 72 + 2 * cp] = pk_rh(a.z, c.z);
                *(unsigned int*)&x_s[(pix + 3) * 72 + 2 * cp] = pk_rh(a.w, c.w);
            }
    }

    int lane = tid & 63, w = tid >> 6;
    int q = lane >> 4, nl = lane & 15;

    s16x8 A[3][2];
#pragma unroll
    for (int CT = 0; CT < 3; CT++) {
        const float* wsrc;
        float scale = 1.0f;
        if (CT == 0) {
            if (nl < 8) { wsrc = w_theta + nl * 64; scale = 1.44269504f; }
            else        { wsrc = w_phi + (nl - 8) * 64; }
        } else if (CT == 1) wsrc = w_g + nl * 64;
        else                wsrc = w_g + (16 + nl) * 64;
#pragma unroll
        for (int ks = 0; ks < 2; ks++) {
            const float4* p4 = (const float4*)(wsrc + 32 * ks + 8 * q);
            float4 a0 = p4[0], a1 = p4[1];
            s16x8 f;
            f[0] = (short)f32_bf16(a0.x * scale); f[1] = (short)f32_bf16(a0.y * scale);
            f[2] = (short)f32_bf16(a0.z * scale); f[3] = (short)f32_bf16(a0.w * scale);
            f[4] = (short)f32_bf16(a1.x * scale); f[5] = (short)f32_bf16(a1.y * scale);
            f[6] = (short)f32_bf16(a1.z * scale); f[7] = (short)f32_bf16(a1.w * scale);
            A[CT][ks] = f;
        }
    }
    __syncthreads();

    f32x4 acc[3][2];
#pragma unroll
    for (int ti = 0; ti < 2; ti++) {
        int tile = w + 4 * ti;
        const unsigned short* rb = x_s + (16 * tile + nl) * 72;
        s16x8 B0 = *(const s16x8*)(rb + 8 * q);
        s16x8 B1 = *(const s16x8*)(rb + 32 + 8 * q);
#pragma unroll
        for (int CT = 0; CT < 3; CT++) {
            f32x4 d = (f32x4){0.f, 0.f, 0.f, 0.f};
            d = __builtin_amdgcn_mfma_f32_16x16x32_bf16(A[CT][0], B0, d, 0, 0, 0);
            d = __builtin_amdgcn_mfma_f32_16x16x32_bf16(A[CT][1], B1, d, 0, 0, 0);
            acc[CT][ti] = d;
        }
    }

    if (q < 2) {
        unsigned short* thb = (unsigned short*)thG + ((size_t)b << 14) * 8;
#pragma unroll
        for (int ti = 0; ti < 2; ti++) {
            int n = (2 * mh + ti) * 128 + 64 * ph + 16 * w + nl;
            uint2 tv;
            tv.x = pk_bf16(acc[0][ti][0], acc[0][ti][1]);
            tv.y = pk_bf16(acc[0][ti][2], acc[0][ti][3]);
            *(uint2*)(thb + (size_t)n * 8 + 4 * q) = tv;
        }
    }

    float pool[3][4];
#pragma unroll
    for (int CT = 0; CT < 3; CT++)
#pragma unroll
        for (int r = 0; r < 4; r++) {
            float a = fmaxf(acc[CT][0][r], acc[CT][1][r]);
            pool[CT][r] = fmaxf(a, __shfl_xor(a, 1));
        }

    int mm = 8 * w + (nl >> 1);
    int mbase = mh * 64 + ph * 32;
    if ((nl & 1) == 0) {
        if (q >= 2) {
            uint2 pv;
            pv.x = pk_bf16(pool[0][0], pool[0][1]);
            pv.y = pk_bf16(pool[0][2], pool[0][3]);
            *(uint2*)((unsigned short*)phG + ((size_t)(b * 4096 + mbase + mm)) * 8 + (q - 2) * 4) = pv;
        }
        int p = 8 * ((mm >> 2) & 3) + 4 * ((mm >> 4) & 1) + (mm & 3);
        int mstore = mbase + p;
#pragma unroll
        for (int CT = 1; CT < 3; CT++)
#pragma unroll
            for (int r = 0; r < 4; r++) {
                int cg = 16 * (CT - 1) + 4 * q + r;
                ((unsigned short*)gG)[((size_t)(b * 32 + cg) << 12) + mstore] =
                    f32_bf16(pool[CT][r]);
            }
    }
}

// ---------------- attn: K16 score -> exp2 -> K16 PV, dbuf staging ----------------
// Grid 512 = b(4) x n-tile(128). Block 512 thr = 8 waves x 16 n, full m.
#define GSTR 528                 // g row stride bytes (256 m bf16 + 16 pad)
#define GBUF (32 * GSTR)         // one g buffer: 16896 B

__global__ __launch_bounds__(512) void attn_kernel(
    const __hip_bfloat16* __restrict__ thG, const __hip_bfloat16* __restrict__ phG,
    const __hip_bfloat16* __restrict__ gG,
    const float* __restrict__ w_o, const float* __restrict__ gamma,
    const float* __restrict__ x, float* __restrict__ out)
{
    __shared__ __align__(16) unsigned char smem[2 * GBUF];   // 33792 B
    unsigned char* O_s = smem;   // epilogue overlay [128][80 B]

    int tid = threadIdx.x, lane = tid & 63, w = tid >> 6;   // w: 0..7
    int q = lane >> 4, nl = lane & 15;
    int bx = blockIdx.x;
    int b  = bx >> 7;
    int n0 = (bx & 127) << 7;
    int nw = n0 + w * 16;

    const unsigned short* thb = (const unsigned short*)thG + ((size_t)b << 14) * 8;
    const unsigned short* phb = (const unsigned short*)phG + ((size_t)b << 12) * 8;
    const unsigned short* ggb = (const unsigned short*)gG + ((size_t)b << 17);

    // theta B-frag (K16): B[k=c=4q+j][col=n=nl]; q2/j0 = shift (cancels)
    s16x4 BT = (s16x4){0, 0, 0, 0};
    if (q < 2) {
        uint2 t = *(const uint2*)(thb + (size_t)(nw + nl) * 8 + 4 * q);
        BT = *(s16x4*)&t;
    } else if (q == 2) BT[0] = (short)0xC167;   // bf16(-14.4375)
    // phi A-frag const part: q2/j0 -> k=8 slot = 1.0
    s16x4 Fc = (s16x4){0, 0, 0, 0};
    if (q == 2) Fc[0] = (short)0x3F80;
    // ones A-frag for the l-sum MFMA
    const short one = (short)0x3F80;
    s16x4 ONES = (s16x4){one, one, one, one};

    f32x4 acc0 = (f32x4){0.f, 0.f, 0.f, 0.f};
    f32x4 acc1 = (f32x4){0.f, 0.f, 0.f, 0.f};
    f32x4 lacc = (f32x4){0.f, 0.f, 0.f, 0.f};

    int cs = tid & 31, ss = tid >> 5;            // staging row / 32B segment
    const unsigned short* gsrc = ggb + ((size_t)cs << 12) + ss * 16;
    unsigned int doff = cs * GSTR + ss * 32;

    // preload + stage st 0 into buf 0
    uint4 r0, r1;
    {
        const uint4* src = (const uint4*)gsrc;
        r0 = src[0]; r1 = src[1];
        uint4* dst = (uint4*)(smem + doff);
        dst[0] = r0; dst[1] = r1;
    }
    __syncthreads();

    for (int st = 0; st < 16; st++) {
        const unsigned char* cur = smem + (st & 1) * GBUF;
        int m0 = st << 8;
        if (st < 15) {   // prefetch next st's g into registers (latency hidden)
            const uint4* src = (const uint4*)(gsrc + m0 + 256);
            r0 = src[0]; r1 = src[1];
        }
#pragma unroll
        for (int cc = 0; cc < 8; cc++) {
            int mloc = cc << 5;
            int mg = m0 + mloc;
            s16x4 F0 = Fc, F1 = Fc;
            if (q < 2) {
                uint2 u = *(const uint2*)(phb + (size_t)(mg + nl) * 8 + 4 * q);
                F0 = *(s16x4*)&u;
                uint2 v = *(const uint2*)(phb + (size_t)(mg + 16 + nl) * 8 + 4 * q);
                F1 = *(s16x4*)&v;
            }
            f32x4 z = (f32x4){0.f, 0.f, 0.f, 0.f};
            f32x4 sc0 = __builtin_amdgcn_mfma_f32_16x16x16bf16_1k(F0, BT, z, 0, 0, 0);
            f32x4 sc1 = __builtin_amdgcn_mfma_f32_16x16x16bf16_1k(F1, BT, z, 0, 0, 0);
            float e0 = __builtin_amdgcn_exp2f(sc0[0]);
            float e1 = __builtin_amdgcn_exp2f(sc0[1]);
            float e2 = __builtin_amdgcn_exp2f(sc0[2]);
            float e3 = __builtin_amdgcn_exp2f(sc0[3]);
            float f0 = __builtin_amdgcn_exp2f(sc1[0]);
            float f1 = __builtin_amdgcn_exp2f(sc1[1]);
            float f2 = __builtin_amdgcn_exp2f(sc1[2]);
            float f3 = __builtin_amdgcn_exp2f(sc1[3]);
            uint2 u0 = make_uint2(pk_tr(e0, e1), pk_tr(e2, e3));  // m=4q+r
            uint2 u1 = make_uint2(pk_tr(f0, f1), pk_tr(f2, f3));  // m=16+4q+r
            s16x4 P0 = *(s16x4*)&u0;
            s16x4 P1 = *(s16x4*)&u1;
            // l-sum via MFMA (k-sum is mapping-independent)
            lacc = __builtin_amdgcn_mfma_f32_16x16x16bf16_1k(ONES, P0, lacc, 0, 0, 0);
            lacc = __builtin_amdgcn_mfma_f32_16x16x16bf16_1k(ONES, P1, lacc, 0, 0, 0);
            // pi-permuted g: one b128 per c-row = [frag-a | frag-b]
            s16x8 G0 = *(const s16x8*)(cur + nl * GSTR + (mloc + 8 * q) * 2);
            s16x8 G1 = *(const s16x8*)(cur + (nl + 16) * GSTR + (mloc + 8 * q) * 2);
            s16x4 G0a = __builtin_shufflevector(G0, G0, 0, 1, 2, 3);
            s16x4 G0b = __builtin_shufflevector(G0, G0, 4, 5, 6, 7);
            s16x4 G1a = __builtin_shufflevector(G1, G1, 0, 1, 2, 3);
            s16x4 G1b = __builtin_shufflevector(G1, G1, 4, 5, 6, 7);
            acc0 = __builtin_amdgcn_mfma_f32_16x16x16bf16_1k(G0a, P0, acc0, 0, 0, 0);
            acc0 = __builtin_amdgcn_mfma_f32_16x16x16bf16_1k(G0b, P1, acc0, 0, 0, 0);
            acc1 = __builtin_amdgcn_mfma_f32_16x16x16bf16_1k(G1a, P0, acc1, 0, 0, 0);
            acc1 = __builtin_amdgcn_mfma_f32_16x16x16bf16_1k(G1b, P1, acc1, 0, 0, 0);
        }
        if (st < 15) {   // stage prefetched g into the other buffer
            uint4* dst = (uint4*)(smem + ((st + 1) & 1) * GBUF + doff);
            dst[0] = r0; dst[1] = r1;
        }
        __syncthreads();   // single barrier per st
    }

    // softmax normalize: lacc regs all equal the full m-sum for col n=nl
    float linv = 1.0f / lacc[0];
    acc0 *= linv;
    acc1 *= linv;

    // w_o A-frags: A[row=cc=16g4+nl][k=c=8q+j]
    s16x8 WO[4];
#pragma unroll
    for (int g4 = 0; g4 < 4; g4++) {
        const float4* wr = (const float4*)(w_o + (size_t)(g4 * 16 + nl) * 32 + q * 8);
        float4 a0 = wr[0], a1 = wr[1];
        WO[g4][0] = (short)f32_bf16(a0.x); WO[g4][1] = (short)f32_bf16(a0.y);
        WO[g4][2] = (short)f32_bf16(a0.z); WO[g4][3] = (short)f32_bf16(a0.w);
        WO[g4][4] = (short)f32_bf16(a1.x); WO[g4][5] = (short)f32_bf16(a1.y);
        WO[g4][6] = (short)f32_bf16(a1.z); WO[g4][7] = (short)f32_bf16(a1.w);
    }
    float gam = gamma[0];

    // O_s overlay (last loop barrier precedes this; rows are wave-local)
    int n_loc = w * 16 + nl;
    {
        uint2 ov;
        ov.x = pk_bf16(acc0[0], acc0[1]);
        ov.y = pk_bf16(acc0[2], acc0[3]);
        *(uint2*)(O_s + n_loc * 80 + q * 8) = ov;           // c = 4q..4q+3
        ov.x = pk_bf16(acc1[0], acc1[1]);
        ov.y = pk_bf16(acc1[2], acc1[3]);
        *(uint2*)(O_s + n_loc * 80 + 32 + q * 8) = ov;      // c = 16+4q..
    }
    s16x8 OB = *(const s16x8*)(O_s + n_loc * 80 + q * 16);  // wave-local rows
#pragma unroll
    for (int g4 = 0; g4 < 4; g4++) {
        f32x4 d = (f32x4){0.f, 0.f, 0.f, 0.f};
        d = __builtin_amdgcn_mfma_f32_16x16x32_bf16(WO[g4], OB, d, 0, 0, 0);
#pragma unroll
        for (int r = 0; r < 4; r++) {
            int cc = g4 * 16 + q * 4 + r;
            size_t gi = (((size_t)(b * 64 + cc)) << 14) + nw + nl;
            out[gi] = gam * d[r] + x[gi];
        }
    }
}

extern "C" void kernel_launch(void* const* d_in, const int* in_sizes, int n_in,
                              void* d_out, int out_size, void* d_ws, size_t ws_size,
                              hipStream_t stream) {
    const float* x       = (const float*)d_in[0];
    const float* w_theta = (const float*)d_in[1];
    const float* w_phi   = (const float*)d_in[2];
    const float* w_g     = (const float*)d_in[3];
    const float* w_o     = (const float*)d_in[4];
    const float* gamma   = (const float*)d_in[5];
    float* out = (float*)d_out;

    __hip_bfloat16* thG = (__hip_bfloat16*)d_ws;        // 4*16384*8 = 1 MB
    __hip_bfloat16* phG = thG + 524288;                 // 4*4096*8  = 256 KB
    __hip_bfloat16* gG  = phG + 131072;                 // 4*32*4096 = 1 MB

    proj_kernel<<<512, 256, 0, stream>>>(x, w_theta, w_phi, w_g, thG, phG, gG);
    attn_kernel<<<512, 512, 0, stream>>>(thG, phG, gG, w_o, gamma, x, out);
}

// Round 11
// 130.526 us; speedup vs baseline: 1.3249x; 1.1770x over previous
//
#include <hip/hip_runtime.h>
#include <hip/hip_bf16.h>

// SAGAN self-attention, MI355X gfx950. B=4, C=64, H=W=128, N=16384, M=4096.
// fp32 in/out. Round 11: r8 compute mix (K32 score ~4.85cyc, VALU l, K16 PV
// only for the layout-matched path) + async global_load_lds dbuf staging of
// g (XOR-swizzled source, GROW=512) and phi (linear), 1 barrier/st.
// Verified MFMA layouts: A[row=lane&15][k=8q+j(K32)/4q+j(K16)],
// B same k-map col=lane&15, C/D[row=4q+r][col=lane&15].

typedef __attribute__((ext_vector_type(4))) float f32x4;
typedef __attribute__((ext_vector_type(8))) short s16x8;
typedef __attribute__((ext_vector_type(4))) short s16x4;

__device__ __forceinline__ unsigned short f32_bf16(float f) {
    unsigned int u = __float_as_uint(f);
    return (unsigned short)((u + 0x7fffu + ((u >> 16) & 1u)) >> 16);  // RNE
}
__device__ __forceinline__ unsigned int pk_bf16(float a, float b) {
    return (unsigned int)f32_bf16(a) | ((unsigned int)f32_bf16(b) << 16);
}
__device__ __forceinline__ unsigned int pk_rh(float a, float b) {   // round-half-up
    unsigned int au = __float_as_uint(a) + 0x8000u;
    unsigned int bu = __float_as_uint(b) + 0x8000u;
    return __builtin_amdgcn_perm(bu, au, 0x07060302u);
}
__device__ __forceinline__ unsigned int pk_tr(float a, float b) {   // truncate
    return __builtin_amdgcn_perm(__float_as_uint(b), __float_as_uint(a), 0x07060302u);
}
// async 16B/lane global->LDS DMA; lds dest = wave-uniform base + lane*16
__device__ __forceinline__ void async16(const void* g, void* l) {
    __builtin_amdgcn_global_load_lds(
        (const __attribute__((address_space(1))) unsigned int*)g,
        (__attribute__((address_space(3))) unsigned int*)l, 16, 0, 0);
}

// ---------------- proj: theta/phi/g 1x1 conv + 2x2 maxpool, MFMA ----------------
// (verbatim round 10 — passed; emits pi-permuted gG)
__global__ __launch_bounds__(256) void proj_kernel(
    const float* __restrict__ x,
    const float* __restrict__ w_theta, const float* __restrict__ w_phi,
    const float* __restrict__ w_g,
    __hip_bfloat16* __restrict__ thG,   // [b][n][8]  (theta * log2e)
    __hip_bfloat16* __restrict__ phG,   // [b][m][8]
    __hip_bfloat16* __restrict__ gG)    // [b][32][4096], pi-permuted per 32-m chunk
{
    __shared__ __align__(16) unsigned short x_s[128 * 72];  // [pix][c], 144 B rows
    int tid = threadIdx.x;
    int bx = blockIdx.x;
    int b = bx >> 7, mh = (bx >> 1) & 63, ph = bx & 1;

    {   // phase 1: float4 loads (c-pair per thread), packed u32 LDS transpose
        int cp = tid >> 3, s = tid & 7;
        const float* xb = x + ((size_t)b << 20) + (size_t)(2 * mh) * 128 + 64 * ph;
        const float* p0r = xb + ((size_t)(2 * cp) << 14);
        const float* p1r = p0r + (1 << 14);
#pragma unroll
        for (int py = 0; py < 2; py++)
#pragma unroll
            for (int t = 0; t < 2; t++) {
                int pxl = 4 * s + 32 * t;
                float4 a = *(const float4*)(p0r + py * 128 + pxl);
                float4 c = *(const float4*)(p1r + py * 128 + pxl);
                int pix = py * 64 + pxl;
                *(unsigned int*)&x_s[(pix + 0) * 72 + 2 * cp] = pk_rh(a.x, c.x);
                *(unsigned int*)&x_s[(pix + 1) * 72 + 2 * cp] = pk_rh(a.y, c.y);
                *(unsigned int*)&x_s[(pix + 2) * 72 + 2 * cp] = pk_rh(a.z, c.z);
                *(unsigned int*)&x_s[(pix + 3) * 72 + 2 * cp] = pk_rh(a.w, c.w);
            }
    }

    int lane = tid & 63, w = tid >> 6;
    int q = lane >> 4, nl = lane & 15;

    s16x8 A[3][2];
#pragma unroll
    for (int CT = 0; CT < 3; CT++) {
        const float* wsrc;
        float scale = 1.0f;
        if (CT == 0) {
            if (nl < 8) { wsrc = w_theta + nl * 64; scale = 1.44269504f; }
            else        { wsrc = w_phi + (nl - 8) * 64; }
        } else if (CT == 1) wsrc = w_g + nl * 64;
        else                wsrc = w_g + (16 + nl) * 64;
#pragma unroll
        for (int ks = 0; ks < 2; ks++) {
            const float4* p4 = (const float4*)(wsrc + 32 * ks + 8 * q);
            float4 a0 = p4[0], a1 = p4[1];
            s16x8 f;
            f[0] = (short)f32_bf16(a0.x * scale); f[1] = (short)f32_bf16(a0.y * scale);
            f[2] = (short)f32_bf16(a0.z * scale); f[3] = (short)f32_bf16(a0.w * scale);
            f[4] = (short)f32_bf16(a1.x * scale); f[5] = (short)f32_bf16(a1.y * scale);
            f[6] = (short)f32_bf16(a1.z * scale); f[7] = (short)f32_bf16(a1.w * scale);
            A[CT][ks] = f;
        }
    }
    __syncthreads();

    f32x4 acc[3][2];
#pragma unroll
    for (int ti = 0; ti < 2; ti++) {
        int tile = w + 4 * ti;
        const unsigned short* rb = x_s + (16 * tile + nl) * 72;
        s16x8 B0 = *(const s16x8*)(rb + 8 * q);
        s16x8 B1 = *(const s16x8*)(rb + 32 + 8 * q);
#pragma unroll
        for (int CT = 0; CT < 3; CT++) {
            f32x4 d = (f32x4){0.f, 0.f, 0.f, 0.f};
            d = __builtin_amdgcn_mfma_f32_16x16x32_bf16(A[CT][0], B0, d, 0, 0, 0);
            d = __builtin_amdgcn_mfma_f32_16x16x32_bf16(A[CT][1], B1, d, 0, 0, 0);
            acc[CT][ti] = d;
        }
    }

    if (q < 2) {
        unsigned short* thb = (unsigned short*)thG + ((size_t)b << 14) * 8;
#pragma unroll
        for (int ti = 0; ti < 2; ti++) {
            int n = (2 * mh + ti) * 128 + 64 * ph + 16 * w + nl;
            uint2 tv;
            tv.x = pk_bf16(acc[0][ti][0], acc[0][ti][1]);
            tv.y = pk_bf16(acc[0][ti][2], acc[0][ti][3]);
            *(uint2*)(thb + (size_t)n * 8 + 4 * q) = tv;
        }
    }

    float pool[3][4];
#pragma unroll
    for (int CT = 0; CT < 3; CT++)
#pragma unroll
        for (int r = 0; r < 4; r++) {
            float a = fmaxf(acc[CT][0][r], acc[CT][1][r]);
            pool[CT][r] = fmaxf(a, __shfl_xor(a, 1));
        }

    int mm = 8 * w + (nl >> 1);
    int mbase = mh * 64 + ph * 32;
    if ((nl & 1) == 0) {
        if (q >= 2) {
            uint2 pv;
            pv.x = pk_bf16(pool[0][0], pool[0][1]);
            pv.y = pk_bf16(pool[0][2], pool[0][3]);
            *(uint2*)((unsigned short*)phG + ((size_t)(b * 4096 + mbase + mm)) * 8 + (q - 2) * 4) = pv;
        }
        int p = 8 * ((mm >> 2) & 3) + 4 * ((mm >> 4) & 1) + (mm & 3);
        int mstore = mbase + p;
#pragma unroll
        for (int CT = 1; CT < 3; CT++)
#pragma unroll
            for (int r = 0; r < 4; r++) {
                int cg = 16 * (CT - 1) + 4 * q + r;
                ((unsigned short*)gG)[((size_t)(b * 32 + cg) << 12) + mstore] =
                    f32_bf16(pool[CT][r]);
            }
    }
}

// ---------------- attn: K32 score -> exp2 -> K16 PV, async DMA dbuf ----------------
// Grid 512 = b(4) x n-tile(128). Block 512 thr = 8 waves x 16 n, full m.
// LDS: g dbuf 2x16384 (rows GROW=512B, XOR-swizzled slots) + phi dbuf 2x4096.
__global__ __launch_bounds__(512) void attn_kernel(
    const __hip_bfloat16* __restrict__ thG, const __hip_bfloat16* __restrict__ phG,
    const __hip_bfloat16* __restrict__ gG,
    const float* __restrict__ w_o, const float* __restrict__ gamma,
    const float* __restrict__ x, float* __restrict__ out)
{
    __shared__ __align__(16) unsigned char smem[2 * 16384 + 2 * 4096];  // 40960 B
    unsigned char* O_s = smem;   // epilogue overlay [128][80 B] (g buf0 region)

    int tid = threadIdx.x, lane = tid & 63, w = tid >> 6;   // w: 0..7
    int q = lane >> 4, nl = lane & 15;
    int bx = blockIdx.x;
    int b  = bx >> 7;
    int n0 = (bx & 127) << 7;
    int nw = n0 + w * 16;

    const unsigned short* thb = (const unsigned short*)thG + ((size_t)b << 14) * 8;
    const unsigned short* phb = (const unsigned short*)phG + ((size_t)b << 12) * 8;
    const unsigned short* ggb = (const unsigned short*)gG + ((size_t)b << 17);

    // theta B-frag (K32): B[k=c=8q+j][col=n=nl]; q1/j0 = shift (cancels)
    s16x8 BT = (s16x8){0, 0, 0, 0, 0, 0, 0, 0};
    if (q == 0)      BT = *(const s16x8*)(thb + (size_t)(nw + nl) * 8);
    else if (q == 1) BT[0] = (short)0xC167;   // bf16(-14.4375)
    // phi A-frag const part: q1/j0 -> k=8 slot = 1.0
    s16x8 Fc = (s16x8){0, 0, 0, 0, 0, 0, 0, 0};
    if (q == 1) Fc[0] = (short)0x3F80;

    f32x4 acc0 = (f32x4){0.f, 0.f, 0.f, 0.f};
    f32x4 acc1 = (f32x4){0.f, 0.f, 0.f, 0.f};
    float l = 0.f;

    // async staging: wave w stages g rows {2w,2w+1} and {2w+16,2w+17};
    // lane i -> LDS slot i&31 of row (i>>5); source slot = (i&31) XOR row.
    int crow0 = 2 * w + (lane >> 5);          // 0..15
    int crow1 = crow0 + 16;                   // 16..31
    const unsigned short* gsrc0 = ggb + ((size_t)crow0 << 12) + 8 * ((lane & 31) ^ crow0);
    const unsigned short* gsrc1 = ggb + ((size_t)crow1 << 12) + 8 * ((lane & 31) ^ crow1);
    const unsigned short* psrc  = phb + (size_t)((w & 3) * 64 + lane) * 8;
    unsigned char* ldsg0 = smem + w * 1024;           // + buf*16384
    unsigned char* ldsg1 = smem + 8192 + w * 1024;
    unsigned char* ldsp  = smem + 32768 + (w & 3) * 1024;   // + buf*4096

    // pre-stage st 0 -> buf 0
    async16(gsrc0, ldsg0);
    async16(gsrc1, ldsg1);
    if (w < 4) async16(psrc, ldsp);
    __syncthreads();

    for (int st = 0; st < 16; st++) {
        const unsigned char* gcur = smem + (st & 1) * 16384;
        const unsigned char* pcur = smem + 32768 + (st & 1) * 4096;
        if (st < 15) {   // issue next st's DMA into the other buffers (no wait)
            int mo = (st + 1) << 8;           // g element offset (256/st)
            int nb = (st + 1) & 1;
            async16(gsrc0 + mo, ldsg0 + nb * 16384);
            async16(gsrc1 + mo, ldsg1 + nb * 16384);
            if (w < 4) async16(psrc + (size_t)mo * 8, ldsp + nb * 4096);
        }
#pragma unroll
        for (int cc = 0; cc < 8; cc++) {
            int mloc = cc << 5;
            s16x8 F0 = Fc, F1 = Fc;
            if (q == 0) {   // phi A-frags from LDS (linear rows, 2-way free)
                F0 = *(const s16x8*)(pcur + (mloc + nl) * 16);
                F1 = *(const s16x8*)(pcur + (mloc + 16 + nl) * 16);
            }
            f32x4 z = (f32x4){0.f, 0.f, 0.f, 0.f};
            f32x4 sc0 = __builtin_amdgcn_mfma_f32_16x16x32_bf16(F0, BT, z, 0, 0, 0);
            f32x4 sc1 = __builtin_amdgcn_mfma_f32_16x16x32_bf16(F1, BT, z, 0, 0, 0);
            float e0 = __builtin_amdgcn_exp2f(sc0[0]);
            float e1 = __builtin_amdgcn_exp2f(sc0[1]);
            float e2 = __builtin_amdgcn_exp2f(sc0[2]);
            float e3 = __builtin_amdgcn_exp2f(sc0[3]);
            float f0 = __builtin_amdgcn_exp2f(sc1[0]);
            float f1 = __builtin_amdgcn_exp2f(sc1[1]);
            float f2 = __builtin_amdgcn_exp2f(sc1[2]);
            float f3 = __builtin_amdgcn_exp2f(sc1[3]);
            l += ((e0 + e1) + (e2 + e3)) + ((f0 + f1) + (f2 + f3));
            uint2 u0 = make_uint2(pk_tr(e0, e1), pk_tr(e2, e3));  // m=4q+r
            uint2 u1 = make_uint2(pk_tr(f0, f1), pk_tr(f2, f3));  // m=16+4q+r
            s16x4 P0 = *(s16x4*)&u0;
            s16x4 P1 = *(s16x4*)&u1;
            // pi-permuted g, XOR-swizzled slots: one b128 per c-row = [frag-a|frag-b]
            int t = (cc << 2) + q;
            s16x8 G0 = *(const s16x8*)(gcur + nl * 512 + ((t ^ nl) << 4));
            s16x8 G1 = *(const s16x8*)(gcur + (nl + 16) * 512 + ((t ^ (nl + 16)) << 4));
            s16x4 G0a = __builtin_shufflevector(G0, G0, 0, 1, 2, 3);
            s16x4 G0b = __builtin_shufflevector(G0, G0, 4, 5, 6, 7);
            s16x4 G1a = __builtin_shufflevector(G1, G1, 0, 1, 2, 3);
            s16x4 G1b = __builtin_shufflevector(G1, G1, 4, 5, 6, 7);
            acc0 = __builtin_amdgcn_mfma_f32_16x16x16bf16_1k(G0a, P0, acc0, 0, 0, 0);
            acc0 = __builtin_amdgcn_mfma_f32_16x16x16bf16_1k(G0b, P1, acc0, 0, 0, 0);
            acc1 = __builtin_amdgcn_mfma_f32_16x16x16bf16_1k(G1a, P0, acc1, 0, 0, 0);
            acc1 = __builtin_amdgcn_mfma_f32_16x16x16bf16_1k(G1b, P1, acc1, 0, 0, 0);
        }
        __syncthreads();   // single barrier/st; drains next-st DMA (vmcnt) too
    }

    // softmax denominator: reduce over quads (lane bits 4,5)
    l += __shfl_xor(l, 16);
    l += __shfl_xor(l, 32);
    float linv = 1.0f / l;
    acc0 *= linv;
    acc1 *= linv;

    // w_o A-frags: A[row=cc=16g4+nl][k=c=8q+j]
    s16x8 WO[4];
#pragma unroll
    for (int g4 = 0; g4 < 4; g4++) {
        const float4* wr = (const float4*)(w_o + (size_t)(g4 * 16 + nl) * 32 + q * 8);
        float4 a0 = wr[0], a1 = wr[1];
        WO[g4][0] = (short)f32_bf16(a0.x); WO[g4][1] = (short)f32_bf16(a0.y);
        WO[g4][2] = (short)f32_bf16(a0.z); WO[g4][3] = (short)f32_bf16(a0.w);
        WO[g4][4] = (short)f32_bf16(a1.x); WO[g4][5] = (short)f32_bf16(a1.y);
        WO[g4][6] = (short)f32_bf16(a1.z); WO[g4][7] = (short)f32_bf16(a1.w);
    }
    float gam = gamma[0];

    // O_s overlay in g-buf0 region (last compute used buf1; post-barrier safe).
    int n_loc = w * 16 + nl;
    {
        uint2 ov;
        ov.x = pk_bf16(acc0[0], acc0[1]);
        ov.y = pk_bf16(acc0[2], acc0[3]);
        *(uint2*)(O_s + n_loc * 80 + q * 8) = ov;           // c = 4q..4q+3
        ov.x = pk_bf16(acc1[0], acc1[1]);
        ov.y = pk_bf16(acc1[2], acc1[3]);
        *(uint2*)(O_s + n_loc * 80 + 32 + q * 8) = ov;      // c = 16+4q..
    }
    s16x8 OB = *(const s16x8*)(O_s + n_loc * 80 + q * 16);  // wave-local rows
#pragma unroll
    for (int g4 = 0; g4 < 4; g4++) {
        f32x4 d = (f32x4){0.f, 0.f, 0.f, 0.f};
        d = __builtin_amdgcn_mfma_f32_16x16x32_bf16(WO[g4], OB, d, 0, 0, 0);
#pragma unroll
        for (int r = 0; r < 4; r++) {
            int cc = g4 * 16 + q * 4 + r;
            size_t gi = (((size_t)(b * 64 + cc)) << 14) + nw + nl;
            out[gi] = gam * d[r] + x[gi];
        }
    }
}

extern "C" void kernel_launch(void* const* d_in, const int* in_sizes, int n_in,
                              void* d_out, int out_size, void* d_ws, size_t ws_size,
                              hipStream_t stream) {
    const float* x       = (const float*)d_in[0];
    const float* w_theta = (const float*)d_in[1];
    const float* w_phi   = (const float*)d_in[2];
    const float* w_g     = (const float*)d_in[3];
    const float* w_o     = (const float*)d_in[4];
    const float* gamma   = (const float*)d_in[5];
    float* out = (float*)d_out;

    __hip_bfloat16* thG = (__hip_bfloat16*)d_ws;        // 4*16384*8 = 1 MB
    __hip_bfloat16* phG = thG + 524288;                 // 4*4096*8  = 256 KB
    __hip_bfloat16* gG  = phG + 131072;                 // 4*32*4096 = 1 MB

    proj_kernel<<<512, 256, 0, stream>>>(x, w_theta, w_phi, w_g, thG, phG, gG);
    attn_kernel<<<512, 512, 0, stream>>>(thG, phG, gG, w_o, gamma, x, out);
}